// Round 2
// baseline (369.992 us; speedup 1.0000x reference)
//
#include <hip/hip_runtime.h>

#define HW 16384

typedef unsigned short ushort_t;
typedef unsigned int uint32;
typedef __attribute__((ext_vector_type(8))) short short8;
typedef __attribute__((ext_vector_type(4))) float floatx4;

__device__ __forceinline__ ushort_t f2bf(float x) {
  uint32 u = __float_as_uint(x);
  u += 0x7fffu + ((u >> 16) & 1u);
  return (ushort_t)(u >> 16);
}

// ---------------------------------------------------------------------------
// K1: binary masks (4x4 erosion/dilation, SAME pad lo=1 hi=2, cv2 border
// semantics) + zero the midsums accumulator (k_pack atomically adds into it).
// ---------------------------------------------------------------------------
__global__ __launch_bounds__(256) void k_masks(const float* __restrict__ m,
                                               float* __restrict__ er,
                                               float* __restrict__ di,
                                               float* __restrict__ midsums) {
  int idx = blockIdx.x * 256 + threadIdx.x;   // 8*16384 total
  if (blockIdx.x < 24) midsums[idx] = 0.f;    // 24*256 = 6144 floats
  int b = idx >> 14;
  int p = idx & (HW - 1);
  int i = p >> 7, j = p & 127;
  const float* mb = m + (b << 14);
  float ermn = 1.f, dimx = 0.f;
  for (int di_ = -1; di_ <= 2; ++di_) {
    int ii = i + di_;
    if (ii < 0 || ii >= 128) continue;
    for (int dj = -1; dj <= 2; ++dj) {
      int jj = j + dj;
      if (jj < 0 || jj >= 128) continue;
      float z = ((double)mb[ii * 128 + jj] > 0.3) ? 1.f : 0.f;
      ermn = fminf(ermn, z);
      dimx = fmaxf(dimx, z);
    }
  }
  er[idx] = ermn;
  di[idx] = dimx;
}

// ---------------------------------------------------------------------------
// K2: streaming pass over feature. Per block: (b, c8 group of 8 channels,
// 1/8th of n). Computes partial S_er/S_tot/S_di for the 8 channels
// (atomicAdd to midsums) AND writes F as bf16 in MFMA-B-fragment-ready
// packed layout: packed[b][c/8][n][c%8]. Each thread stores 4 consecutive
// dwordx4 into one 64B line -> fully coalesced, no LDS needed anywhere.
// ---------------------------------------------------------------------------
__global__ __launch_bounds__(256) void k_pack(const float* __restrict__ f,
                                              const float* __restrict__ er,
                                              const float* __restrict__ di,
                                              ushort_t* __restrict__ packed,
                                              float* __restrict__ midsums) {
  const int bx = blockIdx.x;          // 8 b * 32 c8 * 8 nc = 2048
  const int b = bx >> 8;
  const int c8 = (bx >> 3) & 31;
  const int nc = bx & 7;
  const int t = threadIdx.x;
  const float* fb = f + ((size_t)b << 22) + ((size_t)(c8 * 8) << 14);
  const float* erb = er + ((size_t)b << 14);
  const float* dib = di + ((size_t)b << 14);
  ushort_t* pk = packed + (((size_t)(b * 32 + c8)) << 14) * 8;

  float se[8], st[8], sd[8];
#pragma unroll
  for (int i = 0; i < 8; ++i) { se[i] = 0.f; st[i] = 0.f; sd[i] = 0.f; }

#pragma unroll
  for (int j = 0; j < 2; ++j) {
    int n = nc * 2048 + j * 1024 + t * 4;
    float4 e = *(const float4*)(erb + n);
    float4 dd = *(const float4*)(dib + n);
    float4 row[8];
#pragma unroll
    for (int i = 0; i < 8; ++i) row[i] = *(const float4*)(fb + ((size_t)i << 14) + n);
#pragma unroll
    for (int i = 0; i < 8; ++i) {
      st[i] += (row[i].x + row[i].y) + (row[i].z + row[i].w);
      se[i] += row[i].x * e.x + row[i].y * e.y + row[i].z * e.z + row[i].w * e.w;
      sd[i] += row[i].x * dd.x + row[i].y * dd.y + row[i].z * dd.z + row[i].w * dd.w;
    }
#pragma unroll
    for (int r = 0; r < 4; ++r) {
      uint32 w0 = (uint32)f2bf(((const float*)&row[0])[r]) |
                  ((uint32)f2bf(((const float*)&row[1])[r]) << 16);
      uint32 w1 = (uint32)f2bf(((const float*)&row[2])[r]) |
                  ((uint32)f2bf(((const float*)&row[3])[r]) << 16);
      uint32 w2 = (uint32)f2bf(((const float*)&row[4])[r]) |
                  ((uint32)f2bf(((const float*)&row[5])[r]) << 16);
      uint32 w3 = (uint32)f2bf(((const float*)&row[6])[r]) |
                  ((uint32)f2bf(((const float*)&row[7])[r]) << 16);
      uint4 pkd; pkd.x = w0; pkd.y = w1; pkd.z = w2; pkd.w = w3;
      *(uint4*)(pk + (size_t)(n + r) * 8) = pkd;
    }
  }

#pragma unroll
  for (int i = 0; i < 8; ++i) {
    for (int off = 32; off; off >>= 1) {
      se[i] += __shfl_down(se[i], off);
      st[i] += __shfl_down(st[i], off);
      sd[i] += __shfl_down(sd[i], off);
    }
  }
  if ((t & 63) == 0) {
    float* msb = midsums + (size_t)(b * 256 + c8 * 8) * 3;
#pragma unroll
    for (int i = 0; i < 8; ++i) {
      atomicAdd(&msb[i * 3 + 0], se[i]);
      atomicAdd(&msb[i * 3 + 1], st[i]);
      atomicAdd(&msb[i * 3 + 2], sd[i]);
    }
  }
}

// ---------------------------------------------------------------------------
// K3: per-batch tiny algebra -> W_final (bf16) and bias_eff. Serial loops
// unrolled x8 to pipeline the load->use chains (was latency-bound: 8 blocks,
// 256-deep dependent L2 loads).
// ---------------------------------------------------------------------------
__global__ __launch_bounds__(256) void k_prep(
    const float* __restrict__ midsums, const float* __restrict__ wfeat,
    const float* __restrict__ gf, const float* __restrict__ bfp,
    const float* __restrict__ mfp, const float* __restrict__ vfp,
    const float* __restrict__ wout, const float* __restrict__ g2,
    const float* __restrict__ b2p, const float* __restrict__ m2p,
    const float* __restrict__ v2p, ushort_t* __restrict__ Wbf,
    float* __restrict__ bias_eff) {
  const int b = blockIdx.x;
  const int t = threadIdx.x;
  __shared__ float mid[3][256];
  __shared__ float msc[3][256];
  __shared__ float tl[256], s2l[256], t2l[256];
  __shared__ float ul[3];
  __shared__ float Bm[3][256];
  __shared__ float bias2[256];
  __shared__ float A2[256][3];

  {
    const float* ms = midsums + (size_t)(b * 256 + t) * 3;
    float se = ms[0], st = ms[1], sd = ms[2];
    float m0 = se, m1 = st - sd, m2v = sd - se;
    mid[0][t] = m0; mid[1][t] = m1; mid[2][t] = m2v;
    float s = gf[t] * rsqrtf(vfp[t] + 1e-5f);
    tl[t] = bfp[t] - mfp[t] * s;
    msc[0][t] = m0 * s; msc[1][t] = m1 * s; msc[2][t] = m2v * s;
    float s2 = g2[t] * rsqrtf(v2p[t] + 1e-5f);
    s2l[t] = s2;
    t2l[t] = b2p[t] - m2p[t] * s2;
  }
  __syncthreads();
  if (t < 3) {
    float u = 0.f;
#pragma unroll 8
    for (int c = 0; c < 256; ++c) u += mid[t][c] * tl[c];
    ul[t] = u;
  }
  {
    float b0 = 0.f, b1 = 0.f, b2v = 0.f;
#pragma unroll 8
    for (int o = 0; o < 256; ++o) {
      float wfv = wfeat[o * 256 + t];          // coalesced
      b0 += msc[0][o] * wfv;
      b1 += msc[1][o] * wfv;
      b2v += msc[2][o] * wfv;
    }
    Bm[0][t] = b0; Bm[1][t] = b1; Bm[2][t] = b2v;
  }
  __syncthreads();
  bias2[t] = mid[0][t] * ul[0] + mid[1][t] * ul[1] + mid[2][t] * ul[2];
  __syncthreads();
  {
    const float4* w2 = (const float4*)(wout + t * 512 + 256);  // row o=t, 2nd half
    float a0 = 0.f, a1 = 0.f, a2v = 0.f, bb = 0.f;
#pragma unroll 4
    for (int cq = 0; cq < 64; ++cq) {
      float4 wv = w2[cq];
      int c = cq * 4;
      a0 += wv.x * mid[0][c] + wv.y * mid[0][c + 1] + wv.z * mid[0][c + 2] + wv.w * mid[0][c + 3];
      a1 += wv.x * mid[1][c] + wv.y * mid[1][c + 1] + wv.z * mid[1][c + 2] + wv.w * mid[1][c + 3];
      a2v += wv.x * mid[2][c] + wv.y * mid[2][c + 1] + wv.z * mid[2][c + 2] + wv.w * mid[2][c + 3];
      bb += wv.x * bias2[c] + wv.y * bias2[c + 1] + wv.z * bias2[c + 2] + wv.w * bias2[c + 3];
    }
    A2[t][0] = a0; A2[t][1] = a1; A2[t][2] = a2v;
    bias_eff[b * 256 + t] = s2l[t] * bb + t2l[t];
  }
  __syncthreads();
  {
    float bm0 = Bm[0][t], bm1 = Bm[1][t], bm2 = Bm[2][t];
    ushort_t* Wb = Wbf + ((size_t)b << 16);
#pragma unroll 8
    for (int o = 0; o < 256; ++o) {
      float wv = wout[o * 512 + t];            // coalesced (first half of w_out)
      float val = s2l[o] * (wv + A2[o][0] * bm0 + A2[o][1] * bm1 + A2[o][2] * bm2);
      Wb[o * 256 + t] = f2bf(val);             // coalesced bf16 store
    }
  }
}

// ---------------------------------------------------------------------------
// K4: out[b][o][n] = bias_eff[b][o] + sum_c W[b][o][c] * F[b][c][n].
// A-frags from bf16 W (L2-hot), B-frags as single dwordx4 from the packed
// bf16 layout (lane l15 -> 16 consecutive bytes, 256B/quad coalesced).
// No conversions, no LDS, no barriers -> loads pipeline freely across
// the K loop; purely HBM-bound.
// ---------------------------------------------------------------------------
__global__ __launch_bounds__(256) void k_gemm(const ushort_t* __restrict__ packed,
                                              const ushort_t* __restrict__ Wbf,
                                              const float* __restrict__ bias,
                                              float* __restrict__ out) {
  const int b = blockIdx.x >> 8;
  const int n0 = (blockIdx.x & 255) * 64;
  const int wv = threadIdx.x >> 6;
  const int lane = threadIdx.x & 63;
  const int l15 = lane & 15;
  const int quad = lane >> 4;
  const int obase = wv * 64;
  const ushort_t* pkb = packed + (((size_t)(b * 32)) << 14) * 8;
  const ushort_t* Wb = Wbf + ((size_t)b << 16);
  const float* biasb = bias + (b << 8);

  floatx4 acc[4][4];
#pragma unroll
  for (int ot = 0; ot < 4; ++ot) {
#pragma unroll
    for (int r = 0; r < 4; ++r) {
      float bv = biasb[obase + ot * 16 + quad * 4 + r];
#pragma unroll
      for (int nt = 0; nt < 4; ++nt) acc[ot][nt][r] = bv;
    }
  }

  for (int kc = 0; kc < 256; kc += 32) {
    short8 a[4];
#pragma unroll
    for (int ot = 0; ot < 4; ++ot)
      a[ot] = *(const short8*)(Wb + (size_t)(obase + ot * 16 + l15) * 256 + kc + quad * 8);
    short8 bfr[4];
#pragma unroll
    for (int nt = 0; nt < 4; ++nt)
      bfr[nt] = *(const short8*)(pkb + (((size_t)((kc >> 3) + quad)) << 14) * 8 +
                                 (size_t)(n0 + nt * 16 + l15) * 8);
#pragma unroll
    for (int ot = 0; ot < 4; ++ot)
#pragma unroll
      for (int nt = 0; nt < 4; ++nt)
        acc[ot][nt] = __builtin_amdgcn_mfma_f32_16x16x32_bf16(a[ot], bfr[nt], acc[ot][nt], 0, 0, 0);
  }

  float* ob = out + ((size_t)b << 22);
#pragma unroll
  for (int ot = 0; ot < 4; ++ot)
#pragma unroll
    for (int nt = 0; nt < 4; ++nt)
#pragma unroll
      for (int r = 0; r < 4; ++r)
        ob[(size_t)(obase + ot * 16 + quad * 4 + r) * HW + n0 + nt * 16 + l15] = acc[ot][nt][r];
}

// ---------------------------------------------------------------------------
extern "C" void kernel_launch(void* const* d_in, const int* in_sizes, int n_in,
                              void* d_out, int out_size, void* d_ws, size_t ws_size,
                              hipStream_t stream) {
  (void)in_sizes; (void)n_in; (void)out_size; (void)ws_size;
  const float* feature = (const float*)d_in[0];
  const float* m = (const float*)d_in[1];
  const float* w_feat = (const float*)d_in[2];
  const float* gf = (const float*)d_in[3];
  const float* bf = (const float*)d_in[4];
  const float* mf = (const float*)d_in[5];
  const float* vf = (const float*)d_in[6];
  const float* w_out = (const float*)d_in[7];
  const float* g2 = (const float*)d_in[8];
  const float* b2 = (const float*)d_in[9];
  const float* m2 = (const float*)d_in[10];
  const float* v2 = (const float*)d_in[11];
  float* out = (float*)d_out;

  char* wsb = (char*)d_ws;
  float* er = (float*)wsb;                               // 512 KB
  float* di = (float*)(wsb + (512 << 10));               // 512 KB
  float* midsums = (float*)(wsb + (1 << 20));            // 24 KB
  float* bias_eff = (float*)(wsb + (1 << 20) + (32 << 10));  // 8 KB
  ushort_t* Wbf = (ushort_t*)(wsb + (2 << 20));          // 1 MB
  ushort_t* packed = (ushort_t*)(wsb + (4 << 20));       // 67 MB

  hipLaunchKernelGGL(k_masks, dim3(512), dim3(256), 0, stream, m, er, di, midsums);
  hipLaunchKernelGGL(k_pack, dim3(2048), dim3(256), 0, stream, feature, er, di, packed, midsums);
  hipLaunchKernelGGL(k_prep, dim3(8), dim3(256), 0, stream, midsums, w_feat,
                     gf, bf, mf, vf, w_out, g2, b2, m2, v2, Wbf, bias_eff);
  hipLaunchKernelGGL(k_gemm, dim3(2048), dim3(256), 0, stream, packed, Wbf, bias_eff, out);
}

// Round 3
// 346.663 us; speedup vs baseline: 1.0673x; 1.0673x over previous
//
#include <hip/hip_runtime.h>

#define HW 16384
#define LDSP 66   // LDS row stride (floats): even -> 8B-aligned float2 writes;
                  // frag-read bank = (2c+n)%32 -> exact 2-way aliasing = free (m136)

typedef unsigned short ushort_t;
typedef unsigned int uint32;
typedef __attribute__((ext_vector_type(8))) short short8;
typedef __attribute__((ext_vector_type(4))) float floatx4;

__device__ __forceinline__ ushort_t f2bf(float x) {
  uint32 u = __float_as_uint(x);
  u += 0x7fffu + ((u >> 16) & 1u);
  return (ushort_t)(u >> 16);
}

// ---------------------------------------------------------------------------
// K1: binary masks. er = AND over in-bounds 4x4 window (SAME pad lo=1 hi=2,
// border does not erode/dilate, cv2 semantics); di = OR. threshold m > 0.3.
// ---------------------------------------------------------------------------
__global__ __launch_bounds__(256) void k_masks(const float* __restrict__ m,
                                               float* __restrict__ er,
                                               float* __restrict__ di) {
  int idx = blockIdx.x * 256 + threadIdx.x;   // 8*16384 total
  int b = idx >> 14;
  int p = idx & (HW - 1);
  int i = p >> 7, j = p & 127;
  const float* mb = m + (b << 14);
  float ermn = 1.f, dimx = 0.f;
  for (int di_ = -1; di_ <= 2; ++di_) {
    int ii = i + di_;
    if (ii < 0 || ii >= 128) continue;
    for (int dj = -1; dj <= 2; ++dj) {
      int jj = j + dj;
      if (jj < 0 || jj >= 128) continue;
      float z = ((double)mb[ii * 128 + jj] > 0.3) ? 1.f : 0.f;
      ermn = fminf(ermn, z);
      dimx = fmaxf(dimx, z);
    }
  }
  er[idx] = ermn;
  di[idx] = dimx;
}

// ---------------------------------------------------------------------------
// K2: per (b,c): S_er = sum er*f, S_tot = sum f, S_di = sum di*f over HW.
// One block per (b,c); direct writes (block owns its outputs, no atomics).
// er/di are 1 MB total -> L2-resident broadcast reads.
// ---------------------------------------------------------------------------
__global__ __launch_bounds__(256) void k_midsums(const float* __restrict__ f,
                                                 const float* __restrict__ er,
                                                 const float* __restrict__ di,
                                                 float* __restrict__ out) {
  int b = blockIdx.x >> 8;
  int c = blockIdx.x & 255;
  const float4* f4 = (const float4*)(f + ((size_t)(b * 256 + c) << 14));
  const float4* e4 = (const float4*)(er + ((size_t)b << 14));
  const float4* d4 = (const float4*)(di + ((size_t)b << 14));
  int t = threadIdx.x;
  float se = 0.f, st = 0.f, sd = 0.f;
#pragma unroll
  for (int it = 0; it < 16; ++it) {
    int i = it * 256 + t;
    float4 x = f4[i];
    float4 e = e4[i];
    float4 dd = d4[i];
    st += (x.x + x.y) + (x.z + x.w);
    se += x.x * e.x + x.y * e.y + x.z * e.z + x.w * e.w;
    sd += x.x * dd.x + x.y * dd.y + x.z * dd.z + x.w * dd.w;
  }
  __shared__ float red[3][4];
  for (int off = 32; off; off >>= 1) {
    se += __shfl_down(se, off);
    st += __shfl_down(st, off);
    sd += __shfl_down(sd, off);
  }
  int wave = t >> 6;
  if ((t & 63) == 0) { red[0][wave] = se; red[1][wave] = st; red[2][wave] = sd; }
  __syncthreads();
  if (t == 0) {
    se = red[0][0] + red[0][1] + red[0][2] + red[0][3];
    st = red[1][0] + red[1][1] + red[1][2] + red[1][3];
    sd = red[2][0] + red[2][1] + red[2][2] + red[2][3];
    float* o = out + (size_t)(b * 256 + c) * 3;
    o[0] = se; o[1] = st; o[2] = sd;
  }
}

// ---------------------------------------------------------------------------
// K3: per-batch tiny algebra -> W_final (bf16) and bias_eff.
// ---------------------------------------------------------------------------
__global__ __launch_bounds__(256) void k_prep(
    const float* __restrict__ midsums, const float* __restrict__ wfeat,
    const float* __restrict__ gf, const float* __restrict__ bfp,
    const float* __restrict__ mfp, const float* __restrict__ vfp,
    const float* __restrict__ wout, const float* __restrict__ g2,
    const float* __restrict__ b2p, const float* __restrict__ m2p,
    const float* __restrict__ v2p, ushort_t* __restrict__ Wbf,
    float* __restrict__ bias_eff) {
  const int b = blockIdx.x;
  const int t = threadIdx.x;
  __shared__ float mid[3][256];
  __shared__ float msc[3][256];
  __shared__ float tl[256], s2l[256], t2l[256];
  __shared__ float ul[3];
  __shared__ float Bm[3][256];
  __shared__ float bias2[256];
  __shared__ float A2[256][3];

  {
    const float* ms = midsums + (size_t)(b * 256 + t) * 3;
    float se = ms[0], st = ms[1], sd = ms[2];
    float m0 = se, m1 = st - sd, m2v = sd - se;
    mid[0][t] = m0; mid[1][t] = m1; mid[2][t] = m2v;
    float s = gf[t] * rsqrtf(vfp[t] + 1e-5f);
    tl[t] = bfp[t] - mfp[t] * s;
    msc[0][t] = m0 * s; msc[1][t] = m1 * s; msc[2][t] = m2v * s;
    float s2 = g2[t] * rsqrtf(v2p[t] + 1e-5f);
    s2l[t] = s2;
    t2l[t] = b2p[t] - m2p[t] * s2;
  }
  __syncthreads();
  if (t < 3) {
    float u = 0.f;
#pragma unroll 8
    for (int c = 0; c < 256; ++c) u += mid[t][c] * tl[c];
    ul[t] = u;
  }
  {
    float b0 = 0.f, b1 = 0.f, b2v = 0.f;
#pragma unroll 8
    for (int o = 0; o < 256; ++o) {
      float wfv = wfeat[o * 256 + t];          // coalesced
      b0 += msc[0][o] * wfv;
      b1 += msc[1][o] * wfv;
      b2v += msc[2][o] * wfv;
    }
    Bm[0][t] = b0; Bm[1][t] = b1; Bm[2][t] = b2v;
  }
  __syncthreads();
  bias2[t] = mid[0][t] * ul[0] + mid[1][t] * ul[1] + mid[2][t] * ul[2];
  __syncthreads();
  {
    const float4* w2 = (const float4*)(wout + t * 512 + 256);  // row o=t, 2nd half
    float a0 = 0.f, a1 = 0.f, a2v = 0.f, bb = 0.f;
#pragma unroll 4
    for (int cq = 0; cq < 64; ++cq) {
      float4 wv = w2[cq];
      int c = cq * 4;
      a0 += wv.x * mid[0][c] + wv.y * mid[0][c + 1] + wv.z * mid[0][c + 2] + wv.w * mid[0][c + 3];
      a1 += wv.x * mid[1][c] + wv.y * mid[1][c + 1] + wv.z * mid[1][c + 2] + wv.w * mid[1][c + 3];
      a2v += wv.x * mid[2][c] + wv.y * mid[2][c + 1] + wv.z * mid[2][c + 2] + wv.w * mid[2][c + 3];
      bb += wv.x * bias2[c] + wv.y * bias2[c + 1] + wv.z * bias2[c + 2] + wv.w * bias2[c + 3];
    }
    A2[t][0] = a0; A2[t][1] = a1; A2[t][2] = a2v;
    bias_eff[b * 256 + t] = s2l[t] * bb + t2l[t];
  }
  __syncthreads();
  {
    float bm0 = Bm[0][t], bm1 = Bm[1][t], bm2 = Bm[2][t];
    ushort_t* Wb = Wbf + ((size_t)b << 16);
#pragma unroll 8
    for (int o = 0; o < 256; ++o) {
      float wv = wout[o * 512 + t];            // coalesced (first half of w_out)
      float val = s2l[o] * (wv + A2[o][0] * bm0 + A2[o][1] * bm1 + A2[o][2] * bm2);
      Wb[o * 256 + t] = f2bf(val);             // coalesced bf16 store
    }
  }
}

// ---------------------------------------------------------------------------
// K4: out[b][o][n] = bias_eff[b][o] + sum_c W[b][o][c] * F[b][c][n].
// Reads F fp32 directly (no packed intermediate): per K-tile stage 64c x 64n
// into LDS (coalesced float4 global loads, prefetched before the barrier),
// B-frags via 8x ds_read_b32 (2-way banked = free) + f2bf; A-frags (bf16 W,
// 1 MB total, L2-hot) straight from global.
// ---------------------------------------------------------------------------
__global__ __launch_bounds__(256) void k_gemm(const float* __restrict__ f,
                                              const ushort_t* __restrict__ Wbf,
                                              const float* __restrict__ bias,
                                              float* __restrict__ out) {
  __shared__ float lds[64 * LDSP];
  const int b = blockIdx.x >> 8;
  const int n0 = (blockIdx.x & 255) * 64;
  const int t = threadIdx.x;
  const int wv = t >> 6;
  const int lane = t & 63;
  const int l15 = lane & 15;
  const int quad = lane >> 4;
  const int obase = wv * 64;
  const float* fb = f + ((size_t)b << 22);
  const ushort_t* Wb = Wbf + ((size_t)b << 16);
  const float* biasb = bias + (b << 8);

  const int c_loc = t >> 2;   // 0..63: channel row this thread stages
  const int f4c = t & 3;      // 0..3: which float4 column group

  floatx4 acc[4][4];
#pragma unroll
  for (int ot = 0; ot < 4; ++ot) {
#pragma unroll
    for (int r = 0; r < 4; ++r) {
      float bv = biasb[obase + ot * 16 + quad * 4 + r];
#pragma unroll
      for (int nt = 0; nt < 4; ++nt) acc[ot][nt][r] = bv;
    }
  }

  for (int kc = 0; kc < 256; kc += 64) {
    // prefetch next tile while (other waves') previous compute drains
    const float4* gsrc = (const float4*)(fb + (size_t)(kc + c_loc) * HW + n0);
    float4 v[4];
#pragma unroll
    for (int k = 0; k < 4; ++k) v[k] = gsrc[f4c + 4 * k];
    if (kc) __syncthreads();            // protect LDS reuse
    float* dst = &lds[c_loc * LDSP];
#pragma unroll
    for (int k = 0; k < 4; ++k) {
      int col = (f4c + 4 * k) * 4;
      *(float2*)(dst + col) = make_float2(v[k].x, v[k].y);
      *(float2*)(dst + col + 2) = make_float2(v[k].z, v[k].w);
    }
    __syncthreads();
#pragma unroll
    for (int ks = 0; ks < 2; ++ks) {
      short8 a[4];
#pragma unroll
      for (int ot = 0; ot < 4; ++ot)
        a[ot] = *(const short8*)(Wb + (size_t)(obase + ot * 16 + l15) * 256 +
                                 kc + ks * 32 + quad * 8);
      short8 bfr[4];
#pragma unroll
      for (int nt = 0; nt < 4; ++nt) {
#pragma unroll
        for (int j = 0; j < 8; ++j)
          bfr[nt][j] = (short)f2bf(lds[(ks * 32 + quad * 8 + j) * LDSP + nt * 16 + l15]);
      }
#pragma unroll
      for (int ot = 0; ot < 4; ++ot)
#pragma unroll
        for (int nt = 0; nt < 4; ++nt)
          acc[ot][nt] = __builtin_amdgcn_mfma_f32_16x16x32_bf16(a[ot], bfr[nt], acc[ot][nt], 0, 0, 0);
    }
  }

  float* ob = out + ((size_t)b << 22);
#pragma unroll
  for (int ot = 0; ot < 4; ++ot)
#pragma unroll
    for (int nt = 0; nt < 4; ++nt)
#pragma unroll
      for (int r = 0; r < 4; ++r)
        ob[(size_t)(obase + ot * 16 + quad * 4 + r) * HW + n0 + nt * 16 + l15] = acc[ot][nt][r];
}

// ---------------------------------------------------------------------------
extern "C" void kernel_launch(void* const* d_in, const int* in_sizes, int n_in,
                              void* d_out, int out_size, void* d_ws, size_t ws_size,
                              hipStream_t stream) {
  (void)in_sizes; (void)n_in; (void)out_size; (void)ws_size;
  const float* feature = (const float*)d_in[0];
  const float* m = (const float*)d_in[1];
  const float* w_feat = (const float*)d_in[2];
  const float* gf = (const float*)d_in[3];
  const float* bf = (const float*)d_in[4];
  const float* mf = (const float*)d_in[5];
  const float* vf = (const float*)d_in[6];
  const float* w_out = (const float*)d_in[7];
  const float* g2 = (const float*)d_in[8];
  const float* b2 = (const float*)d_in[9];
  const float* m2 = (const float*)d_in[10];
  const float* v2 = (const float*)d_in[11];
  float* out = (float*)d_out;

  char* wsb = (char*)d_ws;
  float* er = (float*)wsb;                                   // 512 KB
  float* di = (float*)(wsb + (512 << 10));                   // 512 KB
  float* midsums = (float*)(wsb + (1 << 20));                // 24 KB
  float* bias_eff = (float*)(wsb + (1 << 20) + (32 << 10));  // 8 KB
  ushort_t* Wbf = (ushort_t*)(wsb + (2 << 20));              // 1 MB

  hipLaunchKernelGGL(k_masks, dim3(512), dim3(256), 0, stream, m, er, di);
  hipLaunchKernelGGL(k_midsums, dim3(2048), dim3(256), 0, stream, feature, er, di, midsums);
  hipLaunchKernelGGL(k_prep, dim3(8), dim3(256), 0, stream, midsums, w_feat,
                     gf, bf, mf, vf, w_out, g2, b2, m2, v2, Wbf, bias_eff);
  hipLaunchKernelGGL(k_gemm, dim3(2048), dim3(256), 0, stream, feature, Wbf, bias_eff, out);
}